// Round 2
// baseline (842.439 us; speedup 1.0000x reference)
//
#include <hip/hip_runtime.h>
#include <cstdint>
#include <cstddef>

// ---------------------------------------------------------------------------
// Transformer block (B=4, T=2048, C=1024, H=16, D=64) on gfx950.
// Round 1: same as round 0 (acquisition timeout — no signal); x2 moved into
// d_out to cut workspace use to ~104 MB.
// ---------------------------------------------------------------------------

typedef __attribute__((ext_vector_type(8))) __bf16 bf16x8;
typedef __attribute__((ext_vector_type(8))) unsigned short u16x8;
typedef __attribute__((ext_vector_type(4))) float f32x4;

static constexpr int Bn = 4;
static constexpr int Tn = 2048;
static constexpr int Cn = 1024;
static constexpr int Hn = 16;
static constexpr int Dn = 64;

__device__ __forceinline__ unsigned short f2bf(float f) {
    unsigned int u = __builtin_bit_cast(unsigned int, f);
    u += 0x7fffu + ((u >> 16) & 1u);
    return (unsigned short)(u >> 16);
}

#define GLL16(gp, lp) __builtin_amdgcn_global_load_lds( \
    (const __attribute__((address_space(1))) void*)(gp), \
    (__attribute__((address_space(3))) void*)(lp), 16, 0, 0)

// ---------------------------------------------------------------------------
// fp32 -> bf16 conversion (weights)
// ---------------------------------------------------------------------------
__global__ __launch_bounds__(256) void conv_bf16(const float* __restrict__ in,
                                                 unsigned short* __restrict__ out,
                                                 int n4) {
    int i = blockIdx.x * 256 + threadIdx.x;
    if (i < n4) {
        float4 v = ((const float4*)in)[i];
        ushort4 o;
        o.x = f2bf(v.x); o.y = f2bf(v.y); o.z = f2bf(v.z); o.w = f2bf(v.w);
        ((ushort4*)out)[i] = o;
    }
}

// ---------------------------------------------------------------------------
// LayerNorm: fp32 in [rows][1024] -> bf16 out. One block (256 thr) per row.
// ---------------------------------------------------------------------------
__global__ __launch_bounds__(256) void ln_kernel(const float* __restrict__ x,
                                                 const float* __restrict__ g,
                                                 const float* __restrict__ b,
                                                 unsigned short* __restrict__ out) {
    __shared__ float red[8];
    const int row = blockIdx.x;
    const int tid = threadIdx.x;
    const float4 v = ((const float4*)(x + (size_t)row * Cn))[tid];
    float s = v.x + v.y + v.z + v.w;
    float q = v.x * v.x + v.y * v.y + v.z * v.z + v.w * v.w;
    #pragma unroll
    for (int m = 1; m < 64; m <<= 1) {
        s += __shfl_xor(s, m, 64);
        q += __shfl_xor(q, m, 64);
    }
    const int wave = tid >> 6;
    if ((tid & 63) == 0) { red[wave] = s; red[4 + wave] = q; }
    __syncthreads();
    s = red[0] + red[1] + red[2] + red[3];
    q = red[4] + red[5] + red[6] + red[7];
    const float mu  = s * (1.0f / Cn);
    const float var = q * (1.0f / Cn) - mu * mu;
    const float rstd = rsqrtf(var + 1e-5f);
    const float4 gv = ((const float4*)g)[tid];
    const float4 bv = ((const float4*)b)[tid];
    ushort4 o;
    o.x = f2bf((v.x - mu) * rstd * gv.x + bv.x);
    o.y = f2bf((v.y - mu) * rstd * gv.y + bv.y);
    o.z = f2bf((v.z - mu) * rstd * gv.z + bv.z);
    o.w = f2bf((v.w - mu) * rstd * gv.w + bv.w);
    ((ushort4*)(out + (size_t)row * Cn))[tid] = o;
}

// ---------------------------------------------------------------------------
// GEMM: C[M,N] = A[M,K](bf16) @ W[N,K](bf16)^T + bias
//   GELU: apply exact gelu;   RES: out fp32 = res + val, else out bf16
// 128x128 tile, 4 waves (2x2), BK=32, global_load_lds staging.
// ---------------------------------------------------------------------------
template <bool GELU, bool RES>
__global__ __launch_bounds__(256, 2)
void gemm_bt(const unsigned short* __restrict__ A,
             const unsigned short* __restrict__ W,
             const float* __restrict__ bias,
             const float* __restrict__ res,
             void* __restrict__ out,
             int M, int N, int K) {
    __shared__ unsigned short aL[128 * 32];
    __shared__ unsigned short bL[128 * 32];
    const int tid  = threadIdx.x;
    const int lane = tid & 63;
    const int wave = tid >> 6;
    const int wm = wave >> 1, wn = wave & 1;
    const int bm0 = blockIdx.y * 128, bn0 = blockIdx.x * 128;
    const int l15 = lane & 15, l4 = lane >> 4;

    f32x4 acc[4][4] = {};

    for (int kt = 0; kt < K; kt += 32) {
        #pragma unroll
        for (int i = 0; i < 2; ++i) {
            const int ch = i * 256 + tid;      // 0..511, 16B chunks
            const int r = ch >> 2, c = ch & 3; // row in tile, chunk in row
            GLL16(A + (size_t)(bm0 + r) * K + kt + c * 8, &aL[ch * 8]);
            GLL16(W + (size_t)(bn0 + r) * K + kt + c * 8, &bL[ch * 8]);
        }
        __syncthreads();
        bf16x8 av[4], bv[4];
        #pragma unroll
        for (int mi = 0; mi < 4; ++mi)
            av[mi] = *(const bf16x8*)&aL[(wm * 64 + mi * 16 + l15) * 32 + l4 * 8];
        #pragma unroll
        for (int ni = 0; ni < 4; ++ni)
            bv[ni] = *(const bf16x8*)&bL[(wn * 64 + ni * 16 + l15) * 32 + l4 * 8];
        #pragma unroll
        for (int mi = 0; mi < 4; ++mi)
            #pragma unroll
            for (int ni = 0; ni < 4; ++ni)
                acc[mi][ni] = __builtin_amdgcn_mfma_f32_16x16x32_bf16(
                    av[mi], bv[ni], acc[mi][ni], 0, 0, 0);
        __syncthreads();
    }

    #pragma unroll
    for (int mi = 0; mi < 4; ++mi) {
        #pragma unroll
        for (int ni = 0; ni < 4; ++ni) {
            const int col = bn0 + wn * 64 + ni * 16 + l15;
            const float bvl = bias[col];
            #pragma unroll
            for (int j = 0; j < 4; ++j) {
                const int r = bm0 + wm * 64 + mi * 16 + l4 * 4 + j;
                float v = acc[mi][ni][j] + bvl;
                if (GELU) v = 0.5f * v * (1.0f + erff(v * 0.70710678118f));
                const size_t idx = (size_t)r * N + col;
                if (RES) ((float*)out)[idx] = res[idx] + v;
                else     ((unsigned short*)out)[idx] = f2bf(v);
            }
        }
    }
}

// ---------------------------------------------------------------------------
// Flash attention (non-causal). qkv bf16 [B][T][3*C] (q|k|v each [H][D]).
// Block = one (b,h), 64 q-rows (4 waves x 16). K-tiles of 128 keys.
// ---------------------------------------------------------------------------
__global__ __launch_bounds__(256, 2)
void attn_kernel(const unsigned short* __restrict__ qkv,
                 unsigned short* __restrict__ y) {
    __shared__ unsigned short kL[128 * 64];   // [key][d]
    __shared__ unsigned short vT[64 * 128];   // [d][key]
    __shared__ unsigned short pL[4][16 * 128];// per-wave P [qrow][key]
    const int tid  = threadIdx.x;
    const int lane = tid & 63;
    const int wave = tid >> 6;
    const int l15 = lane & 15, l4 = lane >> 4;
    const int bh = blockIdx.y, b = bh >> 4, h = bh & 15;
    const int q0 = blockIdx.x * 64;
    const size_t base = (size_t)b * Tn * (3 * Cn);

    // Q fragments in registers
    const int tq = q0 + wave * 16 + l15;
    const unsigned short* qp = qkv + base + (size_t)tq * (3 * Cn) + h * Dn;
    const bf16x8 qf0 = *(const bf16x8*)(qp + l4 * 8);
    const bf16x8 qf1 = *(const bf16x8*)(qp + 32 + l4 * 8);

    float mr[4], lr[4];
    f32x4 o[4] = {};
    #pragma unroll
    for (int j = 0; j < 4; ++j) { mr[j] = -1e30f; lr[j] = 0.0f; }

    for (int kt = 0; kt < Tn; kt += 128) {
        // stage K tile: linear [128][64]
        #pragma unroll
        for (int i = 0; i < 4; ++i) {
            const int ch = i * 256 + tid;       // 0..1023
            const int key = ch >> 3, c = ch & 7;
            GLL16(qkv + base + (size_t)(kt + key) * (3 * Cn) + Cn + h * Dn + c * 8,
                  &kL[ch * 8]);
        }
        // stage V transposed: vT[d][key]
        #pragma unroll
        for (int i = 0; i < 4; ++i) {
            const int ch = i * 256 + tid;
            const int key = ch >> 3, c = ch & 7;
            const u16x8 vv = *(const u16x8*)(qkv + base + (size_t)(kt + key) * (3 * Cn)
                                             + 2 * Cn + h * Dn + c * 8);
            #pragma unroll
            for (int j = 0; j < 8; ++j)
                vT[(c * 8 + j) * 128 + key] = vv[j];
        }
        __syncthreads();

        // S = (Q K^T) * scale for this wave's 16 q-rows x 128 keys
        f32x4 s[8];
        #pragma unroll
        for (int ni = 0; ni < 8; ++ni) {
            const bf16x8 kb0 = *(const bf16x8*)&kL[(ni * 16 + l15) * 64 + l4 * 8];
            const bf16x8 kb1 = *(const bf16x8*)&kL[(ni * 16 + l15) * 64 + 32 + l4 * 8];
            f32x4 a = {};
            a = __builtin_amdgcn_mfma_f32_16x16x32_bf16(qf0, kb0, a, 0, 0, 0);
            a = __builtin_amdgcn_mfma_f32_16x16x32_bf16(qf1, kb1, a, 0, 0, 0);
            s[ni] = a * 0.125f;
        }

        // online softmax per row (rows live in 16-lane groups)
        #pragma unroll
        for (int j = 0; j < 4; ++j) {
            float tm = -1e30f;
            #pragma unroll
            for (int ni = 0; ni < 8; ++ni) tm = fmaxf(tm, s[ni][j]);
            #pragma unroll
            for (int m = 1; m < 16; m <<= 1) tm = fmaxf(tm, __shfl_xor(tm, m, 64));
            const float mn = fmaxf(mr[j], tm);
            const float al = __expf(mr[j] - mn);
            mr[j] = mn;
            float rs = 0.0f;
            #pragma unroll
            for (int ni = 0; ni < 8; ++ni) {
                const float p = __expf(s[ni][j] - mn);
                s[ni][j] = p;
                rs += p;
            }
            #pragma unroll
            for (int m = 1; m < 16; m <<= 1) rs += __shfl_xor(rs, m, 64);
            lr[j] = lr[j] * al + rs;
            #pragma unroll
            for (int di = 0; di < 4; ++di) o[di][j] *= al;
            const int row = l4 * 4 + j;
            #pragma unroll
            for (int ni = 0; ni < 8; ++ni)
                pL[wave][row * 128 + ni * 16 + l15] = f2bf(s[ni][j]);
        }

        // O += P V
        #pragma unroll
        for (int kk = 0; kk < 4; ++kk) {
            const bf16x8 pa = *(const bf16x8*)&pL[wave][l15 * 128 + kk * 32 + l4 * 8];
            #pragma unroll
            for (int di = 0; di < 4; ++di) {
                const bf16x8 vb = *(const bf16x8*)&vT[(di * 16 + l15) * 128 + kk * 32 + l4 * 8];
                o[di] = __builtin_amdgcn_mfma_f32_16x16x32_bf16(pa, vb, o[di], 0, 0, 0);
            }
        }
        __syncthreads();
    }

    // epilogue: y[b][t][h*64+d] = o / l
    #pragma unroll
    for (int di = 0; di < 4; ++di) {
        #pragma unroll
        for (int j = 0; j < 4; ++j) {
            const int t = q0 + wave * 16 + l4 * 4 + j;
            y[(size_t)(b * Tn + t) * Cn + h * Dn + di * 16 + l15] = f2bf(o[di][j] / lr[j]);
        }
    }
}

// ---------------------------------------------------------------------------
extern "C" void kernel_launch(void* const* d_in, const int* in_sizes, int n_in,
                              void* d_out, int out_size, void* d_ws, size_t ws_size,
                              hipStream_t stream) {
    (void)in_sizes; (void)n_in; (void)out_size; (void)ws_size;
    const float* x      = (const float*)d_in[0];
    const float* ln1_g  = (const float*)d_in[1];
    const float* ln1_b  = (const float*)d_in[2];
    const float* ln2_g  = (const float*)d_in[3];
    const float* ln2_b  = (const float*)d_in[4];
    const float* qkv_w  = (const float*)d_in[5];
    const float* qkv_b  = (const float*)d_in[6];
    const float* proj_w = (const float*)d_in[7];
    const float* proj_b = (const float*)d_in[8];
    const float* fc1_w  = (const float*)d_in[9];
    const float* fc1_b  = (const float*)d_in[10];
    const float* fc2_w  = (const float*)d_in[11];
    const float* fc2_b  = (const float*)d_in[12];

    char* ws = (char*)d_ws;
    unsigned short* wq  = (unsigned short*)(ws + 0);          //  0..6 MB
    unsigned short* wp  = (unsigned short*)(ws + 6291456);    //  6..8 MB
    unsigned short* wf1 = (unsigned short*)(ws + 8388608);    //  8..16 MB
    unsigned short* wf2 = (unsigned short*)(ws + 16777216);   // 16..24 MB
    unsigned short* h   = (unsigned short*)(ws + 25165824);   // 24..40 MB
    unsigned short* qkv = (unsigned short*)(ws + 41943040);   // 40..88 MB
    unsigned short* yb  = (unsigned short*)(ws + 92274688);   // 88..104 MB
    unsigned short* act = (unsigned short*)(ws + 41943040);   // 40..104 MB (over qkv+yb)
    float*          x2  = (float*)d_out;                      // residual stream lives in d_out
    // peak ws use: ~104 MB

    const int BT = Bn * Tn; // 8192

    // weights -> bf16
    conv_bf16<<<dim3(3072), dim3(256), 0, stream>>>(qkv_w, wq, 3 * Cn * Cn / 4);
    conv_bf16<<<dim3(1024), dim3(256), 0, stream>>>(proj_w, wp, Cn * Cn / 4);
    conv_bf16<<<dim3(4096), dim3(256), 0, stream>>>(fc1_w, wf1, 4 * Cn * Cn / 4);
    conv_bf16<<<dim3(4096), dim3(256), 0, stream>>>(fc2_w, wf2, 4 * Cn * Cn / 4);

    // LN1
    ln_kernel<<<dim3(BT), dim3(256), 0, stream>>>(x, ln1_g, ln1_b, h);
    // QKV
    gemm_bt<false, false><<<dim3(3 * Cn / 128, BT / 128), dim3(256), 0, stream>>>(
        h, wq, qkv_b, nullptr, qkv, BT, 3 * Cn, Cn);
    // attention
    attn_kernel<<<dim3(Tn / 64, Bn * Hn), dim3(256), 0, stream>>>(qkv, yb);
    // proj + residual -> x2 (fp32, in d_out)
    gemm_bt<false, true><<<dim3(Cn / 128, BT / 128), dim3(256), 0, stream>>>(
        yb, wp, proj_b, x, x2, BT, Cn, Cn);
    // LN2
    ln_kernel<<<dim3(BT), dim3(256), 0, stream>>>(x2, ln2_g, ln2_b, h);
    // fc1 + gelu
    gemm_bt<true, false><<<dim3(4 * Cn / 128, BT / 128), dim3(256), 0, stream>>>(
        h, wf1, fc1_b, nullptr, act, BT, 4 * Cn, Cn);
    // fc2 + residual -> out (fp32), reading res from d_out in-place
    gemm_bt<false, true><<<dim3(Cn / 128, BT / 128), dim3(256), 0, stream>>>(
        act, wf2, fc2_b, x2, (float*)d_out, BT, Cn, 4 * Cn);
}

// Round 3
// 671.894 us; speedup vs baseline: 1.2538x; 1.2538x over previous
//
#include <hip/hip_runtime.h>
#include <cstdint>
#include <cstddef>

// ---------------------------------------------------------------------------
// Transformer block (B=4, T=2048, C=1024, H=16, D=64) on gfx950.
// Round 2: attention LDS bank-conflict fixes (T2 swizzles on K/vT/pL,
// conflict-free V transpose staging, setprio around MFMA). GEMMs unchanged.
// ---------------------------------------------------------------------------

typedef __attribute__((ext_vector_type(8))) __bf16 bf16x8;
typedef __attribute__((ext_vector_type(8))) unsigned short u16x8;
typedef __attribute__((ext_vector_type(4))) float f32x4;

static constexpr int Bn = 4;
static constexpr int Tn = 2048;
static constexpr int Cn = 1024;
static constexpr int Hn = 16;
static constexpr int Dn = 64;

__device__ __forceinline__ unsigned short f2bf(float f) {
    unsigned int u = __builtin_bit_cast(unsigned int, f);
    u += 0x7fffu + ((u >> 16) & 1u);
    return (unsigned short)(u >> 16);
}

#define GLL16(gp, lp) __builtin_amdgcn_global_load_lds( \
    (const __attribute__((address_space(1))) void*)(gp), \
    (__attribute__((address_space(3))) void*)(lp), 16, 0, 0)

// ---------------------------------------------------------------------------
// fp32 -> bf16 conversion (weights)
// ---------------------------------------------------------------------------
__global__ __launch_bounds__(256) void conv_bf16(const float* __restrict__ in,
                                                 unsigned short* __restrict__ out,
                                                 int n4) {
    int i = blockIdx.x * 256 + threadIdx.x;
    if (i < n4) {
        float4 v = ((const float4*)in)[i];
        ushort4 o;
        o.x = f2bf(v.x); o.y = f2bf(v.y); o.z = f2bf(v.z); o.w = f2bf(v.w);
        ((ushort4*)out)[i] = o;
    }
}

// ---------------------------------------------------------------------------
// LayerNorm: fp32 in [rows][1024] -> bf16 out. One block (256 thr) per row.
// ---------------------------------------------------------------------------
__global__ __launch_bounds__(256) void ln_kernel(const float* __restrict__ x,
                                                 const float* __restrict__ g,
                                                 const float* __restrict__ b,
                                                 unsigned short* __restrict__ out) {
    __shared__ float red[8];
    const int row = blockIdx.x;
    const int tid = threadIdx.x;
    const float4 v = ((const float4*)(x + (size_t)row * Cn))[tid];
    float s = v.x + v.y + v.z + v.w;
    float q = v.x * v.x + v.y * v.y + v.z * v.z + v.w * v.w;
    #pragma unroll
    for (int m = 1; m < 64; m <<= 1) {
        s += __shfl_xor(s, m, 64);
        q += __shfl_xor(q, m, 64);
    }
    const int wave = tid >> 6;
    if ((tid & 63) == 0) { red[wave] = s; red[4 + wave] = q; }
    __syncthreads();
    s = red[0] + red[1] + red[2] + red[3];
    q = red[4] + red[5] + red[6] + red[7];
    const float mu  = s * (1.0f / Cn);
    const float var = q * (1.0f / Cn) - mu * mu;
    const float rstd = rsqrtf(var + 1e-5f);
    const float4 gv = ((const float4*)g)[tid];
    const float4 bv = ((const float4*)b)[tid];
    ushort4 o;
    o.x = f2bf((v.x - mu) * rstd * gv.x + bv.x);
    o.y = f2bf((v.y - mu) * rstd * gv.y + bv.y);
    o.z = f2bf((v.z - mu) * rstd * gv.z + bv.z);
    o.w = f2bf((v.w - mu) * rstd * gv.w + bv.w);
    ((ushort4*)(out + (size_t)row * Cn))[tid] = o;
}

// ---------------------------------------------------------------------------
// GEMM: C[M,N] = A[M,K](bf16) @ W[N,K](bf16)^T + bias  (unchanged from R1)
// ---------------------------------------------------------------------------
template <bool GELU, bool RES>
__global__ __launch_bounds__(256, 2)
void gemm_bt(const unsigned short* __restrict__ A,
             const unsigned short* __restrict__ W,
             const float* __restrict__ bias,
             const float* __restrict__ res,
             void* __restrict__ out,
             int M, int N, int K) {
    __shared__ unsigned short aL[128 * 32];
    __shared__ unsigned short bL[128 * 32];
    const int tid  = threadIdx.x;
    const int lane = tid & 63;
    const int wave = tid >> 6;
    const int wm = wave >> 1, wn = wave & 1;
    const int bm0 = blockIdx.y * 128, bn0 = blockIdx.x * 128;
    const int l15 = lane & 15, l4 = lane >> 4;

    f32x4 acc[4][4] = {};

    for (int kt = 0; kt < K; kt += 32) {
        #pragma unroll
        for (int i = 0; i < 2; ++i) {
            const int ch = i * 256 + tid;      // 0..511, 16B chunks
            const int r = ch >> 2, c = ch & 3; // row in tile, chunk in row
            GLL16(A + (size_t)(bm0 + r) * K + kt + c * 8, &aL[ch * 8]);
            GLL16(W + (size_t)(bn0 + r) * K + kt + c * 8, &bL[ch * 8]);
        }
        __syncthreads();
        bf16x8 av[4], bv[4];
        #pragma unroll
        for (int mi = 0; mi < 4; ++mi)
            av[mi] = *(const bf16x8*)&aL[(wm * 64 + mi * 16 + l15) * 32 + l4 * 8];
        #pragma unroll
        for (int ni = 0; ni < 4; ++ni)
            bv[ni] = *(const bf16x8*)&bL[(wn * 64 + ni * 16 + l15) * 32 + l4 * 8];
        #pragma unroll
        for (int mi = 0; mi < 4; ++mi)
            #pragma unroll
            for (int ni = 0; ni < 4; ++ni)
                acc[mi][ni] = __builtin_amdgcn_mfma_f32_16x16x32_bf16(
                    av[mi], bv[ni], acc[mi][ni], 0, 0, 0);
        __syncthreads();
    }

    #pragma unroll
    for (int mi = 0; mi < 4; ++mi) {
        #pragma unroll
        for (int ni = 0; ni < 4; ++ni) {
            const int col = bn0 + wn * 64 + ni * 16 + l15;
            const float bvl = bias[col];
            #pragma unroll
            for (int j = 0; j < 4; ++j) {
                const int r = bm0 + wm * 64 + mi * 16 + l4 * 4 + j;
                float v = acc[mi][ni][j] + bvl;
                if (GELU) v = 0.5f * v * (1.0f + erff(v * 0.70710678118f));
                const size_t idx = (size_t)r * N + col;
                if (RES) ((float*)out)[idx] = res[idx] + v;
                else     ((unsigned short*)out)[idx] = f2bf(v);
            }
        }
    }
}

// ---------------------------------------------------------------------------
// Flash attention (non-causal). qkv bf16 [B][T][3*C] (q|k|v each [H][D]).
// Block = one (b,h), 64 q-rows (4 waves x 16). K-tiles of 128 keys.
// R2: all LDS tiles XOR-swizzled at 16B-slot granularity.
//   kL: [key][64]  slot(8 elems) ^= key&7   (staged via pre-swizzled source)
//   vT: [d][128]   slot(8 keys)  ^= d&15    (write: one d-row x 64 keys/wave)
//   pL: [q][128]   slot(8 keys)  ^= q&15
// ---------------------------------------------------------------------------
__global__ __launch_bounds__(256, 2)
void attn_kernel(const unsigned short* __restrict__ qkv,
                 unsigned short* __restrict__ y) {
    __shared__ unsigned short kL[128 * 64];   // [key][d] swizzled
    __shared__ unsigned short vT[64 * 128];   // [d][key] swizzled
    __shared__ unsigned short pL[4][16 * 128];// per-wave P [qrow][key] swizzled
    const int tid  = threadIdx.x;
    const int lane = tid & 63;
    const int wave = tid >> 6;
    const int l15 = lane & 15, l4 = lane >> 4;
    const int bh = blockIdx.y, b = bh >> 4, h = bh & 15;
    const int q0 = blockIdx.x * 64;
    const size_t base = (size_t)b * Tn * (3 * Cn);

    // Q fragments in registers
    const int tq = q0 + wave * 16 + l15;
    const unsigned short* qp = qkv + base + (size_t)tq * (3 * Cn) + h * Dn;
    const bf16x8 qf0 = *(const bf16x8*)(qp + l4 * 8);
    const bf16x8 qf1 = *(const bf16x8*)(qp + 32 + l4 * 8);

    float mr[4], lr[4];
    f32x4 o[4] = {};
    #pragma unroll
    for (int j = 0; j < 4; ++j) { mr[j] = -1e30f; lr[j] = 0.0f; }

    for (int kt = 0; kt < Tn; kt += 128) {
        // stage K tile: LDS linear dest, swizzled GLOBAL source (rule #21).
        // LDS slot (key, cs) holds logical slot cs ^ (key&7).
        #pragma unroll
        for (int i = 0; i < 4; ++i) {
            const int ch = i * 256 + tid;       // 0..1023 (16B chunks)
            const int key = ch >> 3, cs = ch & 7;
            const int c_log = cs ^ (key & 7);
            GLL16(qkv + base + (size_t)(kt + key) * (3 * Cn) + Cn + h * Dn + c_log * 8,
                  &kL[ch * 8]);
        }
        // stage V transposed: per wave one d-value x 64 consecutive keys
        // (write 128B-dense per store -> conflict-free), slot ^= d&15.
        #pragma unroll
        for (int i = 0; i < 4; ++i) {
            const int ch = i * 256 + tid;
            const int key = ch & 127, c = ch >> 7;   // c in 0..7
            const u16x8 vv = *(const u16x8*)(qkv + base + (size_t)(kt + key) * (3 * Cn)
                                             + 2 * Cn + h * Dn + c * 8);
            #pragma unroll
            for (int j = 0; j < 8; ++j) {
                const int d = c * 8 + j;
                const int ps = ((key >> 3) ^ (d & 15)) * 8 + (key & 7);
                vT[d * 128 + ps] = vv[j];
            }
        }
        __syncthreads();

        // S = (Q K^T) * scale for this wave's 16 q-rows x 128 keys
        f32x4 s[8];
        __builtin_amdgcn_s_setprio(1);
        #pragma unroll
        for (int ni = 0; ni < 8; ++ni) {
            const int krow = ni * 16 + l15;
            const int ks = (krow & 7) << 3;          // elem-granular swizzle
            const bf16x8 kb0 = *(const bf16x8*)&kL[krow * 64 + ((l4 * 8) ^ ks)];
            const bf16x8 kb1 = *(const bf16x8*)&kL[krow * 64 + ((32 + l4 * 8) ^ ks)];
            f32x4 a = {};
            a = __builtin_amdgcn_mfma_f32_16x16x32_bf16(qf0, kb0, a, 0, 0, 0);
            a = __builtin_amdgcn_mfma_f32_16x16x32_bf16(qf1, kb1, a, 0, 0, 0);
            s[ni] = a * 0.125f;
        }
        __builtin_amdgcn_s_setprio(0);

        // online softmax per row (rows live in 16-lane groups)
        #pragma unroll
        for (int j = 0; j < 4; ++j) {
            float tm = -1e30f;
            #pragma unroll
            for (int ni = 0; ni < 8; ++ni) tm = fmaxf(tm, s[ni][j]);
            #pragma unroll
            for (int m = 1; m < 16; m <<= 1) tm = fmaxf(tm, __shfl_xor(tm, m, 64));
            const float mn = fmaxf(mr[j], tm);
            const float al = __expf(mr[j] - mn);
            mr[j] = mn;
            float rs = 0.0f;
            #pragma unroll
            for (int ni = 0; ni < 8; ++ni) {
                const float p = __expf(s[ni][j] - mn);
                s[ni][j] = p;
                rs += p;
            }
            #pragma unroll
            for (int m = 1; m < 16; m <<= 1) rs += __shfl_xor(rs, m, 64);
            lr[j] = lr[j] * al + rs;
            #pragma unroll
            for (int di = 0; di < 4; ++di) o[di][j] *= al;
            const int row = l4 * 4 + j;
            #pragma unroll
            for (int ni = 0; ni < 8; ++ni) {
                const int col = ni * 16 + l15;
                const int ps = (((col >> 3) ^ row) << 3) | (col & 7);
                pL[wave][row * 128 + ps] = f2bf(s[ni][j]);
            }
        }

        // O += P V
        __builtin_amdgcn_s_setprio(1);
        #pragma unroll
        for (int kk = 0; kk < 4; ++kk) {
            const int pslot = (kk * 4 + l4) ^ l15;   // q-row = l15
            const bf16x8 pa = *(const bf16x8*)&pL[wave][l15 * 128 + pslot * 8];
            #pragma unroll
            for (int di = 0; di < 4; ++di) {
                const int drow = di * 16 + l15;
                const int vslot = (kk * 4 + l4) ^ (drow & 15);
                const bf16x8 vb = *(const bf16x8*)&vT[drow * 128 + vslot * 8];
                o[di] = __builtin_amdgcn_mfma_f32_16x16x32_bf16(pa, vb, o[di], 0, 0, 0);
            }
        }
        __builtin_amdgcn_s_setprio(0);
        __syncthreads();
    }

    // epilogue: y[b][t][h*64+d] = o / l
    #pragma unroll
    for (int di = 0; di < 4; ++di) {
        #pragma unroll
        for (int j = 0; j < 4; ++j) {
            const int t = q0 + wave * 16 + l4 * 4 + j;
            y[(size_t)(b * Tn + t) * Cn + h * Dn + di * 16 + l15] = f2bf(o[di][j] / lr[j]);
        }
    }
}

// ---------------------------------------------------------------------------
extern "C" void kernel_launch(void* const* d_in, const int* in_sizes, int n_in,
                              void* d_out, int out_size, void* d_ws, size_t ws_size,
                              hipStream_t stream) {
    (void)in_sizes; (void)n_in; (void)out_size; (void)ws_size;
    const float* x      = (const float*)d_in[0];
    const float* ln1_g  = (const float*)d_in[1];
    const float* ln1_b  = (const float*)d_in[2];
    const float* ln2_g  = (const float*)d_in[3];
    const float* ln2_b  = (const float*)d_in[4];
    const float* qkv_w  = (const float*)d_in[5];
    const float* qkv_b  = (const float*)d_in[6];
    const float* proj_w = (const float*)d_in[7];
    const float* proj_b = (const float*)d_in[8];
    const float* fc1_w  = (const float*)d_in[9];
    const float* fc1_b  = (const float*)d_in[10];
    const float* fc2_w  = (const float*)d_in[11];
    const float* fc2_b  = (const float*)d_in[12];

    char* ws = (char*)d_ws;
    unsigned short* wq  = (unsigned short*)(ws + 0);          //  0..6 MB
    unsigned short* wp  = (unsigned short*)(ws + 6291456);    //  6..8 MB
    unsigned short* wf1 = (unsigned short*)(ws + 8388608);    //  8..16 MB
    unsigned short* wf2 = (unsigned short*)(ws + 16777216);   // 16..24 MB
    unsigned short* h   = (unsigned short*)(ws + 25165824);   // 24..40 MB
    unsigned short* qkv = (unsigned short*)(ws + 41943040);   // 40..88 MB
    unsigned short* yb  = (unsigned short*)(ws + 92274688);   // 88..104 MB
    unsigned short* act = (unsigned short*)(ws + 41943040);   // 40..104 MB (over qkv+yb)
    float*          x2  = (float*)d_out;                      // residual stream lives in d_out
    // peak ws use: ~104 MB

    const int BT = Bn * Tn; // 8192

    // weights -> bf16
    conv_bf16<<<dim3(3072), dim3(256), 0, stream>>>(qkv_w, wq, 3 * Cn * Cn / 4);
    conv_bf16<<<dim3(1024), dim3(256), 0, stream>>>(proj_w, wp, Cn * Cn / 4);
    conv_bf16<<<dim3(4096), dim3(256), 0, stream>>>(fc1_w, wf1, 4 * Cn * Cn / 4);
    conv_bf16<<<dim3(4096), dim3(256), 0, stream>>>(fc2_w, wf2, 4 * Cn * Cn / 4);

    // LN1
    ln_kernel<<<dim3(BT), dim3(256), 0, stream>>>(x, ln1_g, ln1_b, h);
    // QKV
    gemm_bt<false, false><<<dim3(3 * Cn / 128, BT / 128), dim3(256), 0, stream>>>(
        h, wq, qkv_b, nullptr, qkv, BT, 3 * Cn, Cn);
    // attention
    attn_kernel<<<dim3(Tn / 64, Bn * Hn), dim3(256), 0, stream>>>(qkv, yb);
    // proj + residual -> x2 (fp32, in d_out)
    gemm_bt<false, true><<<dim3(Cn / 128, BT / 128), dim3(256), 0, stream>>>(
        yb, wp, proj_b, x, x2, BT, Cn, Cn);
    // LN2
    ln_kernel<<<dim3(BT), dim3(256), 0, stream>>>(x2, ln2_g, ln2_b, h);
    // fc1 + gelu
    gemm_bt<true, false><<<dim3(4 * Cn / 128, BT / 128), dim3(256), 0, stream>>>(
        h, wf1, fc1_b, nullptr, act, BT, 4 * Cn, Cn);
    // fc2 + residual -> out (fp32), reading res from d_out in-place
    gemm_bt<false, true><<<dim3(Cn / 128, BT / 128), dim3(256), 0, stream>>>(
        act, wf2, fc2_b, x2, (float*)d_out, BT, Cn, 4 * Cn);
}